// Round 9
// baseline (886.413 us; speedup 1.0000x reference)
//
#include <hip/hip_runtime.h>
#include <cfloat>

// VectorQuantizer: z_in [16,256,64,64] fp32, emb [1024,256] fp32
#define HW      4096
#define DIM     256
#define KCODES  1024
#define NVEC    65536
#define OUTHALF 16777216

#define MARGIN  4e-3f   // > deterministic bf16-approx worst-case (2.5e-3) + ref ulp(256) band
#define CANDMAX 16

typedef __attribute__((ext_vector_type(8))) short bf16x8;
typedef __attribute__((ext_vector_type(4))) float f32x4;

// forces x to be materialized (rounded) — prevents mul+add fma contraction
#define FBAR(x) asm volatile("" : "+v"(x))

__device__ __forceinline__ unsigned short f2bf(float f) {  // RNE f32->bf16 (no NaN/inf in data)
  unsigned int u = __builtin_bit_cast(unsigned int, f);
  return (unsigned short)((u + 0x7fffu + ((u >> 16) & 1u)) >> 16);
}

// numpy pairwise_sum replication for sum of 128 squares (stride in elements)
__device__ __forceinline__ float pairwise_sq_128(const float* __restrict__ p, long stride) {
  float r[8];
  #pragma unroll
  for (int j = 0; j < 8; ++j) {
    float v = p[(size_t)j * stride];
    float s = v * v; FBAR(s);
    r[j] = s;
  }
  for (int i = 8; i < 128; i += 8) {
    #pragma unroll
    for (int j = 0; j < 8; ++j) {
      float v = p[(size_t)(i + j) * stride];
      float s = v * v; FBAR(s);
      r[j] += s;
    }
  }
  return ((r[0] + r[1]) + (r[2] + r[3])) + ((r[4] + r[5]) + (r[6] + r[7]));
}

// ---------------- Z_n = fl32 sum(z_n^2), numpy tree; 2 threads/vector ----------------
__global__ __launch_bounds__(256) void zsq_kernel(const float* __restrict__ zin,
                                                  float* __restrict__ zsq) {
  __shared__ float ph[2][128];
  const int v = threadIdx.x & 127;
  const int h = threadIdx.x >> 7;
  const int n  = blockIdx.x * 128 + v;
  const int b  = n >> 12;
  const int hw = n & 4095;
  const float* p = zin + (size_t)b * DIM * HW + hw + (size_t)h * 128 * HW;
  ph[h][v] = pairwise_sq_128(p, HW);
  __syncthreads();
  if (threadIdx.x < 128)
    zsq[blockIdx.x * 128 + threadIdx.x] = ph[0][threadIdx.x] + ph[1][threadIdx.x];
}

// ---------------- esq + e_bf16 conversion ----------------
__global__ void esq_e_kernel(const float* __restrict__ emb, float* __restrict__ esq,
                             unsigned short* __restrict__ ebf) {
  const int k = blockIdx.x * 256 + threadIdx.x;
  if (k >= KCODES) return;
  const float* p = emb + (size_t)k * DIM;
  float h0 = pairwise_sq_128(p, 1);
  float h1 = pairwise_sq_128(p + 128, 1);
  esq[k] = h0 + h1;
  unsigned short* eb = ebf + (size_t)k * DIM;
  for (int g = 0; g < 32; ++g) {
    float4 a = *reinterpret_cast<const float4*>(p + g * 8);
    float4 bq = *reinterpret_cast<const float4*>(p + g * 8 + 4);
    unsigned int w0 = (unsigned int)f2bf(a.x) | ((unsigned int)f2bf(a.y) << 16);
    unsigned int w1 = (unsigned int)f2bf(a.z) | ((unsigned int)f2bf(a.w) << 16);
    unsigned int w2 = (unsigned int)f2bf(bq.x) | ((unsigned int)f2bf(bq.y) << 16);
    unsigned int w3 = (unsigned int)f2bf(bq.z) | ((unsigned int)f2bf(bq.w) << 16);
    *reinterpret_cast<uint4*>(eb + g * 8) = make_uint4(w0, w1, w2, w3);
  }
}

// plain esq for fallback path
__global__ void esq_kernel(const float* __restrict__ emb, float* __restrict__ esq) {
  const int k = blockIdx.x * 256 + threadIdx.x;
  if (k >= KCODES) return;
  const float* p = emb + (size_t)k * DIM;
  float h0 = pairwise_sq_128(p, 1);
  float h1 = pairwise_sq_128(p + 128, 1);
  esq[k] = h0 + h1;
}

// ---------------- prep: BCHW z -> z_t fp32 [NVEC][256] + z bf16 [NVEC][256] ----------------
__global__ __launch_bounds__(256) void prep_z_kernel(const float* __restrict__ zin,
                                                     float* __restrict__ z_t,
                                                     unsigned short* __restrict__ zbf) {
  __shared__ float tile[32][260];
  const int tid = threadIdx.x;
  const int t = blockIdx.x;
  const int b = t >> 7;
  const int dt = (t >> 4) & 7;
  const int hwt = t & 15;
  #pragma unroll
  for (int i = 0; i < 8; ++i) {
    int f = i * 256 + tid;
    int row = f >> 6, c4 = f & 63;
    float4 v = *reinterpret_cast<const float4*>(
        zin + (size_t)(b * 256 + dt * 32 + row) * HW + hwt * 256 + c4 * 4);
    *reinterpret_cast<float4*>(&tile[row][c4 * 4]) = v;
  }
  __syncthreads();
  const int n = b * HW + hwt * 256 + tid;
  float vals[32];
  #pragma unroll
  for (int r = 0; r < 32; ++r) vals[r] = tile[r][tid];
  float* dst = z_t + (size_t)n * DIM + dt * 32;
  #pragma unroll
  for (int q = 0; q < 8; ++q)
    *reinterpret_cast<float4*>(dst + q * 4) =
        make_float4(vals[q * 4], vals[q * 4 + 1], vals[q * 4 + 2], vals[q * 4 + 3]);
  unsigned int uw[16];
  #pragma unroll
  for (int r = 0; r < 16; ++r)
    uw[r] = (unsigned int)f2bf(vals[2 * r]) | ((unsigned int)f2bf(vals[2 * r + 1]) << 16);
  uint4* bdst = reinterpret_cast<uint4*>(zbf + (size_t)n * DIM + dt * 32);
  #pragma unroll
  for (int q = 0; q < 4; ++q)
    bdst[q] = make_uint4(uw[q * 4], uw[q * 4 + 1], uw[q * 4 + 2], uw[q * 4 + 3]);
}

// ---------------- MFMA filter: approx scores + candidate collection ----------------
// s~ = esq[k] - 2 * (z_bf16 . e_bf16)  via mfma_f32_16x16x32_bf16.
// LDS layout per row (64 d per chunk): two 32-k halves; within a half, k=16h+4g+j
// stored at slot 8g+4h+j  ->  lane (l>>4)=g reads its 8 operand bf16 as ONE b128.
// XOR swizzle byte^=((row&7)<<4) kills the [row][128B] bank conflict.
__global__ __launch_bounds__(256) void filter_kernel(
    const unsigned short* __restrict__ zbf, const unsigned short* __restrict__ ebf,
    const float* __restrict__ esq, int* __restrict__ cand_cnt, int* __restrict__ cand_k) {
  __shared__ __align__(16) char smem[49152];
  char* zsb = smem;           // 16 KB: z tile [128 rows][64 d] bf16, slotted+swizzled
  char* esb = smem + 16384;   // 32 KB: e tile [256 rows][64 d]
  const int tid = threadIdx.x;
  const int l = tid & 63;
  const int wid = tid >> 6;
  const int vblk = blockIdx.x >> 2;
  const int kb = blockIdx.x & 3;
  const int n0 = vblk * 128;
  const int k0 = kb * 256;
  const int wn = (wid >> 1) * 64;
  const int wk = (wid & 1) * 128;
  const int lr = l & 15;
  const int lg = l >> 4;

  f32x4 acc[4][8];
  #pragma unroll
  for (int a = 0; a < 4; ++a)
    #pragma unroll
    for (int bq = 0; bq < 8; ++bq) acc[a][bq] = (f32x4)0.f;

  for (int kc = 0; kc < 4; ++kc) {
    #pragma unroll
    for (int i = 0; i < 4; ++i) {           // z: 1024 x 16B chunks
      int f = i * 256 + tid;
      int row = f >> 3, m = f & 7;
      uint4 v = *reinterpret_cast<const uint4*>(zbf + (size_t)(n0 + row) * DIM + kc * 64 + m * 8);
      int base = row * 128 + (m >> 2) * 64 + (m & 1) * 32 + ((m >> 1) & 1) * 8;
      int sw = (row & 7) << 4;
      *reinterpret_cast<uint2*>(zsb + (base ^ sw)) = make_uint2(v.x, v.y);
      *reinterpret_cast<uint2*>(zsb + ((base + 16) ^ sw)) = make_uint2(v.z, v.w);
    }
    #pragma unroll
    for (int i = 0; i < 8; ++i) {           // e: 2048 x 16B chunks
      int f = i * 256 + tid;
      int row = f >> 3, m = f & 7;
      uint4 v = *reinterpret_cast<const uint4*>(ebf + (size_t)(k0 + row) * DIM + kc * 64 + m * 8);
      int base = row * 128 + (m >> 2) * 64 + (m & 1) * 32 + ((m >> 1) & 1) * 8;
      int sw = (row & 7) << 4;
      *reinterpret_cast<uint2*>(esb + (base ^ sw)) = make_uint2(v.x, v.y);
      *reinterpret_cast<uint2*>(esb + ((base + 16) ^ sw)) = make_uint2(v.z, v.w);
    }
    __syncthreads();
    #pragma unroll
    for (int ks = 0; ks < 2; ++ks) {
      bf16x8 af[4], bff[8];
      #pragma unroll
      for (int fm = 0; fm < 4; ++fm) {
        int row = wn + fm * 16 + lr;
        int byte = (row * 128 + ks * 64 + lg * 16) ^ ((row & 7) << 4);
        af[fm] = __builtin_bit_cast(bf16x8, *reinterpret_cast<const uint4*>(zsb + byte));
      }
      #pragma unroll
      for (int fk = 0; fk < 8; ++fk) {
        int row = wk + fk * 16 + lr;
        int byte = (row * 128 + ks * 64 + lg * 16) ^ ((row & 7) << 4);
        bff[fk] = __builtin_bit_cast(bf16x8, *reinterpret_cast<const uint4*>(esb + byte));
      }
      #pragma unroll
      for (int fm = 0; fm < 4; ++fm)
        #pragma unroll
        for (int fk = 0; fk < 8; ++fk)
          acc[fm][fk] = __builtin_amdgcn_mfma_f32_16x16x32_bf16(af[fm], bff[fk], acc[fm][fk], 0, 0, 0);
    }
    __syncthreads();
  }
  // epilogue: per-n block-min + candidate collection (local-min + MARGIN criterion)
  float esql[8];
  #pragma unroll
  for (int fk = 0; fk < 8; ++fk) esql[fk] = esq[k0 + wk + fk * 16 + lr];

  float* bm = reinterpret_cast<float*>(smem);   // [2 k-waves][128 n]
  float gm[4][4];
  #pragma unroll
  for (int fm = 0; fm < 4; ++fm)
    #pragma unroll
    for (int r = 0; r < 4; ++r) {
      float m = esql[0] - 2.f * acc[fm][0][r];
      #pragma unroll
      for (int fk = 1; fk < 8; ++fk) m = fminf(m, esql[fk] - 2.f * acc[fm][fk][r]);
      m = fminf(m, __shfl_xor(m, 1));
      m = fminf(m, __shfl_xor(m, 2));
      m = fminf(m, __shfl_xor(m, 4));
      m = fminf(m, __shfl_xor(m, 8));
      gm[fm][r] = m;
    }
  if (lr == 0) {
    #pragma unroll
    for (int fm = 0; fm < 4; ++fm)
      #pragma unroll
      for (int r = 0; r < 4; ++r)
        bm[(wid & 1) * 128 + (wid >> 1) * 64 + fm * 16 + lg * 4 + r] = gm[fm][r];
  }
  __syncthreads();
  #pragma unroll
  for (int fm = 0; fm < 4; ++fm)
    #pragma unroll
    for (int r = 0; r < 4; ++r) {
      int nl = (wid >> 1) * 64 + fm * 16 + lg * 4 + r;
      float thr = fminf(bm[nl], bm[128 + nl]) + MARGIN;
      #pragma unroll
      for (int fk = 0; fk < 8; ++fk) {
        float s = esql[fk] - 2.f * acc[fm][fk][r];
        if (s <= thr) {
          int n = n0 + nl;
          int kk = k0 + wk + fk * 16 + lr;
          int pos = atomicAdd(&cand_cnt[n], 1);
          if (pos < CANDMAX) cand_k[n * CANDMAX + pos] = kk;
        }
      }
    }
}

// ---------------- exact fp32 re-score of candidates (bit-exact reference chain) ----------------
__global__ __launch_bounds__(256) void rescore_kernel(
    const float* __restrict__ z_t, const float* __restrict__ emb,
    const float* __restrict__ zsq, const float* __restrict__ esq,
    const int* __restrict__ cand_cnt, const int* __restrict__ cand_k,
    int* __restrict__ idx) {
  __shared__ float zl[16][260];
  __shared__ float rs[256];
  __shared__ int rk[256];
  const int tid = threadIdx.x;
  const int blk = blockIdx.x;
  #pragma unroll
  for (int i = 0; i < 4; ++i) {
    int f = i * 256 + tid;
    int row = f >> 6, c4 = f & 63;
    float4 v = *reinterpret_cast<const float4*>(z_t + (size_t)(blk * 16 + row) * DIM + c4 * 4);
    *reinterpret_cast<float4*>(&zl[row][c4 * 4]) = v;
  }
  __syncthreads();
  const int v = tid >> 4, slot = tid & 15;
  const int n = blk * 16 + v;
  const int cnt = cand_cnt[n];
  const float Z = zsq[n];
  float best = FLT_MAX; int bk = 0x7fffffff;
  const float* zr = zl[v];
  if (cnt <= CANDMAX) {
    if (slot < cnt) {
      int k = cand_k[n * CANDMAX + slot];
      const float* er = emb + (size_t)k * DIM;
      float a = 0.f;
      #pragma unroll 8
      for (int d = 0; d < DIM; ++d) a = fmaf(zr[d], er[d], a);   // sequential chain d=0..255
      float t1 = Z - 2.0f * a;                                   // fl(Z - 2mm)
      best = t1 + esq[k];                                        // fl(t + esq)
      bk = k;
    }
  } else {  // overflow: exact scan of all codes (first-occurrence semantics preserved)
    for (int k = slot; k < KCODES; k += 16) {
      const float* er = emb + (size_t)k * DIM;
      float a = 0.f;
      #pragma unroll 8
      for (int d = 0; d < DIM; ++d) a = fmaf(zr[d], er[d], a);
      float t1 = Z - 2.0f * a;
      float s = t1 + esq[k];
      if (s < best || (s == best && k < bk)) { best = s; bk = k; }
    }
  }
  rs[tid] = best; rk[tid] = bk;
  __syncthreads();
  #pragma unroll
  for (int off = 8; off > 0; off >>= 1) {
    if (slot < off) {
      float o = rs[tid + off]; int ok = rk[tid + off];
      if (o < rs[tid] || (o == rs[tid] && ok < rk[tid])) { rs[tid] = o; rk[tid] = ok; }
    }
    __syncthreads();
  }
  if (slot == 0) idx[n] = rk[tid];
}

// ---------------- fallback (round-7 verified path) ----------------
#define TN   128
#define TK   128
#define DC   32
#define ESTR 132
#define KSPLIT 2
struct StageMem { float z[DC][TN]; float e[DC][ESTR]; };
struct MergeMem { float m1[16][TN]; int i1[16][TN]; };
union __align__(16) SmemB { StageMem s; MergeMem m; };

__global__ __launch_bounds__(256) void score_kernel(
    const float* __restrict__ zin, const float* __restrict__ emb,
    const float* __restrict__ zsq, const float* __restrict__ esq,
    float* __restrict__ pm1, int* __restrict__ pi1) {
  __shared__ SmemB sm;
  const int tid = threadIdx.x;
  const int tx = tid & 15;
  const int ty = tid >> 4;
  const int ks   = blockIdx.x & (KSPLIT - 1);
  const int vblk = blockIdx.x >> 1;
  const int n0 = vblk * TN;
  const int b  = n0 >> 12;
  const int hw0 = n0 & 4095;
  const float* zbase = zin + (size_t)b * DIM * HW + hw0;
  float zr2[8];
  #pragma unroll
  for (int r = 0; r < 8; ++r) zr2[r] = zsq[n0 + tx * 8 + r];
  float m1[8]; int i1[8];
  #pragma unroll
  for (int r = 0; r < 8; ++r) { m1[r] = FLT_MAX; i1[r] = 0; }
  for (int kt = 0; kt < (KCODES / KSPLIT) / TK; ++kt) {
    const int k0 = ks * (KCODES / KSPLIT) + kt * TK;
    float acc[8][8];
    #pragma unroll
    for (int r = 0; r < 8; ++r)
      #pragma unroll
      for (int u = 0; u < 8; ++u) acc[r][u] = 0.f;
    float esqr[8];
    #pragma unroll
    for (int u = 0; u < 8; ++u) esqr[u] = esq[k0 + ty * 8 + u];
    for (int dc = 0; dc < DIM / DC; ++dc) {
      #pragma unroll
      for (int i = 0; i < 4; ++i) {
        int f = i * 256 + tid;
        int d  = f >> 5;
        int c4 = f & 31;
        int s  = ((c4 & 1) << 4) | (c4 >> 1);
        float4 v = *reinterpret_cast<const float4*>(zbase + (size_t)(dc * DC + d) * HW + c4 * 4);
        *reinterpret_cast<float4*>(&sm.s.z[d][s * 4]) = v;
      }
      #pragma unroll
      for (int i = 0; i < 4; ++i) {
        int f = i * 256 + tid;
        int r = f & 127;
        int q = f >> 7;
        float4 v = *reinterpret_cast<const float4*>(emb + (size_t)(k0 + r) * DIM + dc * DC + q * 4);
        sm.s.e[q * 4 + 0][r] = v.x;
        sm.s.e[q * 4 + 1][r] = v.y;
        sm.s.e[q * 4 + 2][r] = v.z;
        sm.s.e[q * 4 + 3][r] = v.w;
      }
      __syncthreads();
      #pragma unroll 4
      for (int d = 0; d < DC; ++d) {
        float zr[8], er[8];
        reinterpret_cast<float4&>(zr[0]) = reinterpret_cast<const float4&>(sm.s.z[d][tx * 4]);
        reinterpret_cast<float4&>(zr[4]) = reinterpret_cast<const float4&>(sm.s.z[d][64 + tx * 4]);
        reinterpret_cast<float4&>(er[0]) = reinterpret_cast<const float4&>(sm.s.e[d][ty * 8]);
        reinterpret_cast<float4&>(er[4]) = reinterpret_cast<const float4&>(sm.s.e[d][ty * 8 + 4]);
        #pragma unroll
        for (int r = 0; r < 8; ++r)
          #pragma unroll
          for (int u = 0; u < 8; ++u)
            acc[r][u] = fmaf(zr[r], er[u], acc[r][u]);
      }
      __syncthreads();
    }
    #pragma unroll
    for (int u = 0; u < 8; ++u) {
      const int k = k0 + ty * 8 + u;
      #pragma unroll
      for (int r = 0; r < 8; ++r) {
        float t = zr2[r] - 2.0f * acc[r][u];
        float s = t + esqr[u];
        if (s < m1[r]) { m1[r] = s; i1[r] = k; }
      }
    }
  }
  #pragma unroll
  for (int r = 0; r < 8; ++r) {
    sm.m.m1[ty][tx * 8 + r] = m1[r];
    sm.m.i1[ty][tx * 8 + r] = i1[r];
  }
  __syncthreads();
  if (tid < TN) {
    const int v = tid;
    float bmv = FLT_MAX; int bi = 0x7fffffff;
    for (int t = 0; t < 16; ++t) {
      float a = sm.m.m1[t][v];
      int   ai = sm.m.i1[t][v];
      if (a < bmv || (a == bmv && ai < bi)) { bmv = a; bi = ai; }
    }
    pm1[(size_t)ks * NVEC + n0 + v] = bmv;
    pi1[(size_t)ks * NVEC + n0 + v] = bi;
  }
}

__global__ __launch_bounds__(256) void merge_kernel(const float* __restrict__ pm1,
                                                    const int* __restrict__ pi1,
                                                    int* __restrict__ idx) {
  const int v = blockIdx.x * 256 + threadIdx.x;
  float d0 = pm1[v];
  float d1 = pm1[NVEC + v];
  int   i0 = pi1[v];
  int   i1 = pi1[NVEC + v];
  idx[v] = (d1 < d0) ? i1 : i0;
}

// ---------------- gather + write z_q and quantized (BCHW) ----------------
__global__ __launch_bounds__(256) void output_kernel(
    const float* __restrict__ zin, const float* __restrict__ emb,
    const int* __restrict__ idx, float* __restrict__ out) {
  const int t   = blockIdx.x * 256 + threadIdx.x;
  const int b   = t >> 10;
  const int hw0 = (t & 1023) * 4;
  const int c0  = blockIdx.y * 8;
  const int4 ids = *reinterpret_cast<const int4*>(&idx[(b << 12) + hw0]);
  const float* e0 = emb + (size_t)ids.x * DIM;
  const float* e1 = emb + (size_t)ids.y * DIM;
  const float* e2 = emb + (size_t)ids.z * DIM;
  const float* e3 = emb + (size_t)ids.w * DIM;
  float* zq = out;
  float* qu = out + (size_t)OUTHALF;
  const size_t base = (size_t)b * DIM * HW + hw0;
  #pragma unroll
  for (int c = c0; c < c0 + 8; ++c) {
    const size_t off = base + (size_t)c * HW;
    float4 z4 = *reinterpret_cast<const float4*>(zin + off);
    float4 q4 = make_float4(e0[c], e1[c], e2[c], e3[c]);
    float4 o4;
    o4.x = z4.x + (q4.x - z4.x);
    o4.y = z4.y + (q4.y - z4.y);
    o4.z = z4.z + (q4.z - z4.z);
    o4.w = z4.w + (q4.w - z4.w);
    *reinterpret_cast<float4*>(zq + off) = o4;
    *reinterpret_cast<float4*>(qu + off) = q4;
  }
}

extern "C" void kernel_launch(void* const* d_in, const int* in_sizes, int n_in,
                              void* d_out, int out_size, void* d_ws, size_t ws_size,
                              hipStream_t stream) {
  const float* zin = (const float*)d_in[0];
  const float* emb = (const float*)d_in[1];
  float* out = (float*)d_out;
  char* ws = (char*)d_ws;

  const size_t NEED = 106172416ull;  // z_t + z_bf16 + e_bf16 + zsq + esq + idx + cand_cnt + cand_k
  if (ws_size >= NEED) {
    float*          z_t      = (float*)ws;                               // 64 MB
    unsigned short* zbf      = (unsigned short*)(ws + 67108864);         // 32 MB
    unsigned short* ebf      = (unsigned short*)(ws + 100663296);        // 512 KB
    float*          zsq      = (float*)(ws + 101187584);                 // 256 KB
    float*          esq      = (float*)(ws + 101449728);                 // 4 KB
    int*            idx      = (int*)(ws + 101453824);                   // 256 KB
    int*            cand_cnt = (int*)(ws + 101715968);                   // 256 KB
    int*            cand_k   = (int*)(ws + 101978112);                   // 4 MB

    prep_z_kernel<<<2048, 256, 0, stream>>>(zin, z_t, zbf);
    esq_e_kernel<<<4, 256, 0, stream>>>(emb, esq, ebf);
    zsq_kernel<<<NVEC / 128, 256, 0, stream>>>(zin, zsq);
    hipMemsetAsync(cand_cnt, 0, NVEC * sizeof(int), stream);
    filter_kernel<<<2048, 256, 0, stream>>>(zbf, ebf, esq, cand_cnt, cand_k);
    rescore_kernel<<<4096, 256, 0, stream>>>(z_t, emb, zsq, esq, cand_cnt, cand_k, idx);
    output_kernel<<<dim3(NVEC / 1024, DIM / 8), 256, 0, stream>>>(zin, emb, idx, out);
  } else {
    float* pm1 = (float*)ws;
    int*   pi1 = (int*)(ws + (size_t)KSPLIT * NVEC * 4);
    int*   idx = (int*)(ws + (size_t)2 * KSPLIT * NVEC * 4);
    float* zsq = (float*)(ws + (size_t)(2 * KSPLIT + 1) * NVEC * 4);
    float* esq = (float*)(ws + (size_t)(2 * KSPLIT + 2) * NVEC * 4);
    zsq_kernel<<<NVEC / 128, 256, 0, stream>>>(zin, zsq);
    esq_kernel<<<KCODES / 256, 256, 0, stream>>>(emb, esq);
    score_kernel<<<(NVEC / TN) * KSPLIT, 256, 0, stream>>>(zin, emb, zsq, esq, pm1, pi1);
    merge_kernel<<<NVEC / 256, 256, 0, stream>>>(pm1, pi1, idx);
    output_kernel<<<dim3(NVEC / 1024, DIM / 8), 256, 0, stream>>>(zin, emb, idx, out);
  }
}